// Round 8
// baseline (57.815 us; speedup 1.0000x reference)
//
#include <hip/hip_runtime.h>
#include <hip/hip_bf16.h>
#include <stdint.h>

// Conv2d, B=32, Cin=64, Cout=128, 3x3, stride 1, pad 1, H=W=56, fp32 in/out.
// Reference's mismatched flatten == standard conv with permuted weights:
// Weff for patch elem (c,di,dj) = K[f/192][(f%192)/64][f%64], f = c*9+di*3+dj.
// Reduction order g = di*192 + dj*64 + c => for fixed di, A's K-slice is
// CONTIGUOUS in padded-NHWC layout: byte (w*64+c)*2 within row (i+di).
// r8: BARRIER-FREE main loop. B (147KB weight panel, L1/L2-resident) is
// loaded per-fragment straight to VGPRs (reg double-buffered) — no B LDS
// staging, no main-loop __syncthreads. A staged once per block (2-row block,
// 29.7KB, one barrier total). 896 blocks, 3 waves/SIMD.

#define B_   32
#define CIN  64
#define COUT 128
#define H_   56
#define HP   58          // spatially padded
#define F_   576         // 9*64 reduction length

typedef __attribute__((ext_vector_type(8))) short bf16x8;
typedef __attribute__((ext_vector_type(4))) float f32x4;

#define XP_ELEMS (B_*HP*HP*CIN)          // 6,889,472
#define XP_SLACK 4096                    // covers A-stage tail overread (3KB)
#define XP_TOTAL (XP_ELEMS + XP_SLACK)
#define WG_ELEMS (COUT*F_)               // 73,728
#define WS_NEEDED ((size_t)(XP_TOTAL + WG_ELEMS) * 2)

#define NROW   (B_*HP)                   // 1856 x-row blocks
#define NWBLK  (WG_ELEMS/256)            // 288 weight blocks

// ---------- fused prepass: x NCHW f32 -> padded NHWC bf16; K -> WgT[co][g] ----
__global__ __launch_bounds__(256) void prep_all(const float* __restrict__ x,
                                                const float* __restrict__ K,
                                                __hip_bfloat16* __restrict__ xpT,
                                                __hip_bfloat16* __restrict__ WgT) {
  const int id = blockIdx.x;
  const int t  = threadIdx.x;

  if (id > NROW) {                       // ---- weight permute blocks ----
    int n = (id - (NROW + 1))*256 + t;   // 288 full blocks
    int co = n / F_, g = n % F_;
    int di = g / 192, dj = (g % 192) / 64, c = g & 63;
    int f  = c*9 + di*3 + dj;
    int kh = f / 192, kw = (f % 192) / 64, cc = f & 63;
    WgT[n] = __float2bfloat16(K[(((size_t)kh*3 + kw)*CIN + cc)*COUT + co]);
    return;
  }
  if (id == NROW) {                      // ---- slack zero-fill ----
    bf16x8 z = (bf16x8)0;
    for (int idx = t; idx < XP_SLACK/8; idx += 256)
      ((bf16x8*)(xpT + XP_ELEMS))[idx] = z;
    return;
  }

  const int b = id / HP, h = id % HP;
  __hip_bfloat16* orow = xpT + (size_t)(b*HP + h) * HP * CIN;
  if (h == 0 || h == HP-1) {             // top/bottom pad rows
    bf16x8 z = (bf16x8)0;
    for (int idx = t; idx < HP*CIN/8; idx += 256) ((bf16x8*)orow)[idx] = z;
    return;
  }
  // slot-swizzled scratch: scr[c][slot][4], slot = (w4 + (c>>3)) & 15.
  __shared__ __align__(16) float scr[CIN*64];      // 16 KB
  const float* xrow = x + ((size_t)(b*CIN)*H_ + (h-1)) * H_;
  for (int idx = t; idx < CIN*14; idx += 256) {    // coalesced f32x4 reads
    int c = idx / 14, w4 = idx % 14;
    f32x4 v = *(const f32x4*)(xrow + (size_t)c*(H_*H_) + w4*4);
    *(f32x4*)&scr[c*64 + ((w4 + (c >> 3)) & 15)*4] = v;
  }
  __syncthreads();
  for (int idx = t; idx < HP*8; idx += 256) {      // bf16x8 writes
    int wp = idx >> 3, cg = (idx & 7) * 8;
    __align__(16) __hip_bfloat16 tmp[8];
    if (wp == 0 || wp == HP-1) {
#pragma unroll
      for (int k2 = 0; k2 < 8; ++k2) tmp[k2] = __float2bfloat16(0.f);
    } else {
      int w = wp - 1, sl = w >> 2, off = w & 3;
#pragma unroll
      for (int k2 = 0; k2 < 8; ++k2) {
        int c = cg + k2;
        tmp[k2] = __float2bfloat16(scr[c*64 + ((sl + (c >> 3)) & 15)*4 + off]);
      }
    }
    *(bf16x8*)(orow + (size_t)wp*CIN + cg) = *(const bf16x8*)tmp;
  }
}

// ---------- main: implicit GEMM, block = (b, 2 rows), barrier-free loop ----
// 4 waves 2x2 (wm = output row, wn = co half); per-wave 64j x 64co, acc 4x4.
// A (4 padded rows, 29.7KB) staged once, XOR-swizzled (reads <=2-way = free).
// B fragments loaded global->VGPR per iteration (L1-resident panel), register
// double-buffered. NO barriers after the A-stage one.
__global__ __launch_bounds__(256, 3) void conv_mfma(
    const __hip_bfloat16* __restrict__ xpT,
    const __hip_bfloat16* __restrict__ WgT,
    float* __restrict__ out) {
  __shared__ __align__(16) char lds[32768];
  const int t    = threadIdx.x;
  const int wave = t >> 6;
  const int l    = t & 63;
  const int lr   = l & 15, lq = l >> 4;
  const int wm   = wave >> 1, wn = wave & 1;   // 2x2 wave grid

  // bijective XCD swizzle: 896 = 8 * 112
  const int bid = blockIdx.x;
  const int swz = (bid & 7) * 112 + (bid >> 3);
  const int bb  = swz / 28;
  const int i0  = (swz % 28) * 2;

  f32x4 acc[4][4];
#pragma unroll
  for (int mi = 0; mi < 4; ++mi)
#pragma unroll
    for (int ni = 0; ni < 4; ++ni) acc[mi][ni] = (f32x4)0.f;

  const char* xb = (const char*)xpT + (size_t)(bb*HP + i0) * HP * CIN * 2;

  // ---- stage A once: rows i0..i0+3 = 29,696 B contiguous (8 ops; 3KB tail
  // overread covered by slack); swizzled source, linear dest ----
#pragma unroll
  for (int s = 0; s < 8; ++s) {
    int o = s*4096 + t*16;
    int m = o >> 7;
    const char* src = xb + ((o & ~127) | ((o & 127) ^ ((m & 7) << 4)));
    __builtin_amdgcn_global_load_lds(
        (const __attribute__((address_space(1))) void*)src,
        (__attribute__((address_space(3))) void*)(lds + s*4096 + wave*1024),
        16, 0, 0);
  }
  __syncthreads();                       // the ONLY barrier

  // B per-lane base: co = wn*64 + ni*16 + lr, k-offset lq*16B within chunk
  const char* wB = (const char*)WgT + (size_t)(wn*64 + lr)*1152 + lq*16;

  auto loadB = [&](int hc, bf16x8 (&bq)[4]) {
#pragma unroll
    for (int ni = 0; ni < 4; ++ni)
      bq[ni] = *(const bf16x8*)(wB + ni*(16*1152) + hc*64);
  };

  bf16x8 b0[4], b1[4];
  loadB(0, b0);

#pragma unroll
  for (int hc = 0; hc < 18; ++hc) {
    bf16x8 (&bc)[4] = (hc & 1) ? b1 : b0;          // hc compile-time (unroll)
    bf16x8 (&bn)[4] = (hc & 1) ? b0 : b1;
    if (hc < 17) loadB(hc + 1, bn);                // reg prefetch next chunk
    const int kg  = hc*32;
    const int di  = kg / 192;
    const int rem = kg - di*192;                   // dj*64 + c0 within slab
    bf16x8 a[4];
#pragma unroll
    for (int mi = 0; mi < 4; ++mi) {
      int r   = (wm + di)*HP + mi*16 + lr;         // 128B-row in A tile
      int tot = r*128 + rem*2 + lq*16;
      int adr = (tot & ~127) | ((tot & 127) ^ (((tot >> 7) & 7) << 4));
      a[mi] = *(const bf16x8*)(lds + adr);
    }
    __builtin_amdgcn_s_setprio(1);
#pragma unroll
    for (int mi = 0; mi < 4; ++mi)
#pragma unroll
      for (int ni = 0; ni < 4; ++ni)
        acc[mi][ni] = __builtin_amdgcn_mfma_f32_16x16x32_bf16(
            a[mi], bc[ni], acc[mi][ni], 0, 0, 0);
    __builtin_amdgcn_s_setprio(0);
  }

  // epilogue: C/D layout col=lane&15 -> co, row=(lane>>4)*4+reg -> j
  const int i = i0 + wm;
#pragma unroll
  for (int mi = 0; mi < 4; ++mi) {
    int j0 = mi*16 + lq*4;
    if (j0 < H_) {
#pragma unroll
      for (int ni = 0; ni < 4; ++ni) {
        int co = wn*64 + ni*16 + lr;
        float* dst = out + (((size_t)(bb*COUT + co))*H_ + i)*H_ + j0;
        *(f32x4*)dst = acc[mi][ni];
      }
    }
  }
}

// ---------- fallback (workspace too small): naive fp32 direct ----------
__global__ __launch_bounds__(256) void conv_naive(const float* __restrict__ x,
                                                  const float* __restrict__ K,
                                                  float* __restrict__ out) {
  int idx = blockIdx.x*256 + threadIdx.x;
  const int total = B_*COUT*H_*H_;
  if (idx >= total) return;
  int j = idx % H_, i = (idx / H_) % H_, co = (idx / (H_*H_)) % COUT, b = idx / (H_*H_*COUT);
  float s = 0.f;
  for (int c = 0; c < CIN; ++c)
    for (int di = 0; di < 3; ++di) {
      int ii = i + di - 1;
      if (ii < 0 || ii >= H_) continue;
      for (int dj = 0; dj < 3; ++dj) {
        int jj = j + dj - 1;
        if (jj < 0 || jj >= H_) continue;
        int f = c*9 + di*3 + dj;
        int kh = f / 192, kw = (f % 192) / 64, cc = f & 63;
        s += x[(((size_t)b*CIN + c)*H_ + ii)*H_ + jj] *
             K[(((size_t)kh*3 + kw)*CIN + cc)*COUT + co];
      }
    }
  out[idx] = s;
}

extern "C" void kernel_launch(void* const* d_in, const int* in_sizes, int n_in,
                              void* d_out, int out_size, void* d_ws, size_t ws_size,
                              hipStream_t stream) {
  const float* x = (const float*)d_in[0];
  const float* K = (const float*)d_in[1];
  float* out = (float*)d_out;
  if (ws_size >= WS_NEEDED) {
    __hip_bfloat16* xpT = (__hip_bfloat16*)d_ws;
    __hip_bfloat16* WgT = xpT + XP_TOTAL;
    prep_all<<<NROW + 1 + NWBLK, 256, 0, stream>>>(x, K, xpT, WgT);
    conv_mfma<<<B_*28, 256, 0, stream>>>(xpT, WgT, out);
  } else {
    conv_naive<<<(B_*COUT*H_*H_ + 255)/256, 256, 0, stream>>>(x, K, out);
  }
}

// Round 9
// 39.714 us; speedup vs baseline: 1.4558x; 1.4558x over previous
//
#include <hip/hip_runtime.h>
#include <hip/hip_bf16.h>
#include <stdint.h>

// Conv2d, B=32, Cin=64, Cout=128, 3x3, stride 1, pad 1, H=W=56, fp32 in/out.
// Reference's mismatched flatten == standard conv with permuted weights:
// Weff for patch elem (c,di,dj) = K[f/192][(f%192)/64][f%64], f = c*9+di*3+dj.
// Reduction order g = di*192 + dj*64 + c => for fixed di, A's K-slice is
// CONTIGUOUS in padded-NHWC layout: byte (w*64+c)*2 within row (i+di).
// r9: r6 structure + T3/T4 — B TRIPLE-buffered, staged 2 chunks ahead,
// counted `s_waitcnt vmcnt(2)` + raw s_barrier per iteration (never a full
// drain in the main loop). r8 lesson: B must stage through LDS (per-block
// coalesced burst), NOT per-iteration global loads (L2 same-line storm).

#define B_   32
#define CIN  64
#define COUT 128
#define H_   56
#define HP   58          // spatially padded
#define F_   576         // 9*64 reduction length

typedef __attribute__((ext_vector_type(8))) short bf16x8;
typedef __attribute__((ext_vector_type(4))) float f32x4;

#define XP_ELEMS (B_*HP*HP*CIN)          // 6,889,472
#define XP_SLACK 4096
#define XP_TOTAL (XP_ELEMS + XP_SLACK)
#define WG_ELEMS (COUT*F_)               // 73,728
#define WS_NEEDED ((size_t)(XP_TOTAL + WG_ELEMS) * 2)

#define NROW   (B_*HP)                   // 1856 x-row blocks
#define NWBLK  (WG_ELEMS/256)            // 288 weight blocks

// conv LDS (bytes): A tile [0, 45568); B frag bufs at 45568 + buf*8192 (x3).
#define A_ALLOC 45568
#define LDS_TOT (A_ALLOC + 3*8192)       // 70,144

// ---------- fused prepass: x NCHW f32 -> padded NHWC bf16; K -> WgT[co][g] ----
__global__ __launch_bounds__(256) void prep_all(const float* __restrict__ x,
                                                const float* __restrict__ K,
                                                __hip_bfloat16* __restrict__ xpT,
                                                __hip_bfloat16* __restrict__ WgT) {
  const int id = blockIdx.x;
  const int t  = threadIdx.x;

  if (id > NROW) {                       // ---- weight permute blocks ----
    int n = (id - (NROW + 1))*256 + t;   // 288 full blocks
    int co = n / F_, g = n % F_;
    int di = g / 192, dj = (g % 192) / 64, c = g & 63;
    int f  = c*9 + di*3 + dj;
    int kh = f / 192, kw = (f % 192) / 64, cc = f & 63;
    WgT[n] = __float2bfloat16(K[(((size_t)kh*3 + kw)*CIN + cc)*COUT + co]);
    return;
  }
  if (id == NROW) {                      // ---- slack zero-fill ----
    bf16x8 z = (bf16x8)0;
    for (int idx = t; idx < XP_SLACK/8; idx += 256)
      ((bf16x8*)(xpT + XP_ELEMS))[idx] = z;
    return;
  }

  const int b = id / HP, h = id % HP;
  __hip_bfloat16* orow = xpT + (size_t)(b*HP + h) * HP * CIN;
  if (h == 0 || h == HP-1) {             // top/bottom pad rows
    bf16x8 z = (bf16x8)0;
    for (int idx = t; idx < HP*CIN/8; idx += 256) ((bf16x8*)orow)[idx] = z;
    return;
  }
  // slot-swizzled scratch: scr[c][slot][4], slot = (w4 + (c>>3)) & 15.
  __shared__ __align__(16) float scr[CIN*64];      // 16 KB
  const float* xrow = x + ((size_t)(b*CIN)*H_ + (h-1)) * H_;
  for (int idx = t; idx < CIN*14; idx += 256) {    // coalesced f32x4 reads
    int c = idx / 14, w4 = idx % 14;
    f32x4 v = *(const f32x4*)(xrow + (size_t)c*(H_*H_) + w4*4);
    *(f32x4*)&scr[c*64 + ((w4 + (c >> 3)) & 15)*4] = v;
  }
  __syncthreads();
  for (int idx = t; idx < HP*8; idx += 256) {      // bf16x8 writes
    int wp = idx >> 3, cg = (idx & 7) * 8;
    __align__(16) __hip_bfloat16 tmp[8];
    if (wp == 0 || wp == HP-1) {
#pragma unroll
      for (int k2 = 0; k2 < 8; ++k2) tmp[k2] = __float2bfloat16(0.f);
    } else {
      int w = wp - 1, sl = w >> 2, off = w & 3;
#pragma unroll
      for (int k2 = 0; k2 < 8; ++k2) {
        int c = cg + k2;
        tmp[k2] = __float2bfloat16(scr[c*64 + ((sl + (c >> 3)) & 15)*4 + off]);
      }
    }
    *(bf16x8*)(orow + (size_t)wp*CIN + cg) = *(const bf16x8*)tmp;
  }
}

// ---------- main: implicit GEMM, block = (b, 4 rows), M=256(224 real), N=128
// A staged ONCE (XOR-swizzled src + reads, <=2-way = free). B triple-buffered
// 8KB half-chunks (k=32) in per-lane fragment order (frag ni at
// [ni*1024+lane*16] -> linear reads, 0 conflicts), staged 2 AHEAD; barriers
// are raw s_barrier with counted vmcnt(2) — prefetch stays in flight.
__global__ __launch_bounds__(256, 2) void conv_mfma(
    const __hip_bfloat16* __restrict__ xpT,
    const __hip_bfloat16* __restrict__ WgT,
    float* __restrict__ out) {
  __shared__ __align__(16) char lds[LDS_TOT];
  const int t    = threadIdx.x;
  const int wave = t >> 6;               // wave w -> output row i0+w
  const int l    = t & 63;
  const int lr   = l & 15, lq = l >> 4;

  // bijective XCD swizzle: 448 = 8 * 56
  const int bid = blockIdx.x;
  const int swz = (bid & 7) * 56 + (bid >> 3);
  const int bb  = swz / 14;
  const int i0  = (swz % 14) * 4;

  f32x4 acc[4][8];
#pragma unroll
  for (int mi = 0; mi < 4; ++mi)
#pragma unroll
    for (int ni = 0; ni < 8; ++ni) acc[mi][ni] = (f32x4)0.f;

  const char* xb    = (const char*)xpT + (size_t)(bb*HP + i0) * HP * CIN * 2;
  const char* wbase = (const char*)WgT;

  // ---- stage A once: 45,056 B contiguous, swizzled source, linear dest ----
#pragma unroll
  for (int s = 0; s < 11; ++s) {
    int o = s*4096 + t*16;
    int m = o >> 7;
    const char* src = xb + ((o & ~127) | ((o & 127) ^ ((m & 7) << 4)));
    __builtin_amdgcn_global_load_lds(
        (const __attribute__((address_space(1))) void*)src,
        (__attribute__((address_space(3))) void*)(lds + s*4096 + wave*1024),
        16, 0, 0);
  }

  // B staging source offsets: frag f = s*256+t -> ni = f>>6, lane = f&63;
  // co = ni*16 + (lane&15); src = WgT + hc*64 + co*1152 + (lane>>4)*16.
  int bsrc[2];
#pragma unroll
  for (int s = 0; s < 2; ++s) {
    int f  = s*256 + t;
    int ll = f & 63;
    int co = ((f >> 6)*16) + (ll & 15);
    bsrc[s] = co*1152 + ((ll >> 4)*16);
  }

  auto stageBh = [&](int hc, int buf) {  // 8 KB: WgT[*][hc*32 .. +32) frags
    const char* wg = wbase + hc*64;
    char* Bb = lds + A_ALLOC + buf*8192;
#pragma unroll
    for (int s = 0; s < 2; ++s) {
      __builtin_amdgcn_global_load_lds(
          (const __attribute__((address_space(1))) void*)(wg + bsrc[s]),
          (__attribute__((address_space(3))) void*)(Bb + s*4096 + wave*1024),
          16, 0, 0);
    }
  };

  // prologue: stage B chunks 0 and 1; wait A+B0 (leave B1 in flight)
  stageBh(0, 0);
  stageBh(1, 1);
  asm volatile("s_waitcnt vmcnt(2)" ::: "memory");
  __builtin_amdgcn_s_barrier();

  // ---- main loop: 18 half-chunks of k=32, B triple-buffered, 2 ahead ----
#pragma unroll
  for (int hc = 0; hc < 18; ++hc) {
    if (hc + 2 < 18) stageBh(hc + 2, (hc + 2) % 3);
    const char* Bb = lds + A_ALLOC + (hc % 3)*8192;
    const int kg  = hc*32;
    const int di  = kg / 192;
    const int rem = kg - di*192;         // dj*64 + c0 within di-slab
    bf16x8 a[4], bq[8];
#pragma unroll
    for (int mi = 0; mi < 4; ++mi) {
      int r   = (wave + di)*HP + mi*16 + lr;
      int tot = r*128 + rem*2 + lq*16;
      int adr = (tot & ~127) | ((tot & 127) ^ (((tot >> 7) & 7) << 4));
      a[mi] = *(const bf16x8*)(lds + adr);
    }
#pragma unroll
    for (int ni = 0; ni < 8; ++ni)
      bq[ni] = *(const bf16x8*)(Bb + (ni*64 + l)*16);   // linear: 0 conflicts
    __builtin_amdgcn_s_setprio(1);
#pragma unroll
    for (int mi = 0; mi < 4; ++mi)
#pragma unroll
      for (int ni = 0; ni < 8; ++ni)
        acc[mi][ni] = __builtin_amdgcn_mfma_f32_16x16x32_bf16(
            a[mi], bq[ni], acc[mi][ni], 0, 0, 0);
    __builtin_amdgcn_s_setprio(0);
    // counted sync: next iter's buffer (staged at hc-1) must be landed;
    // leave the 2 loads of stage(hc+2) in flight.
    if (hc < 16) {
      asm volatile("s_waitcnt vmcnt(2)" ::: "memory");
      __builtin_amdgcn_s_barrier();
    } else if (hc == 16) {
      asm volatile("s_waitcnt vmcnt(0)" ::: "memory");
      __builtin_amdgcn_s_barrier();
    }
  }

  // epilogue: C/D layout col=lane&15 -> co, row=(lane>>4)*4+reg -> j
  const int i = i0 + wave;
#pragma unroll
  for (int mi = 0; mi < 4; ++mi) {
    int j0 = mi*16 + lq*4;
    if (j0 < H_) {
#pragma unroll
      for (int ni = 0; ni < 8; ++ni) {
        int co = ni*16 + lr;
        float* dst = out + (((size_t)(bb*COUT + co))*H_ + i)*H_ + j0;
        *(f32x4*)dst = acc[mi][ni];
      }
    }
  }
}

// ---------- fallback (workspace too small): naive fp32 direct ----------
__global__ __launch_bounds__(256) void conv_naive(const float* __restrict__ x,
                                                  const float* __restrict__ K,
                                                  float* __restrict__ out) {
  int idx = blockIdx.x*256 + threadIdx.x;
  const int total = B_*COUT*H_*H_;
  if (idx >= total) return;
  int j = idx % H_, i = (idx / H_) % H_, co = (idx / (H_*H_)) % COUT, b = idx / (H_*H_*COUT);
  float s = 0.f;
  for (int c = 0; c < CIN; ++c)
    for (int di = 0; di < 3; ++di) {
      int ii = i + di - 1;
      if (ii < 0 || ii >= H_) continue;
      for (int dj = 0; dj < 3; ++dj) {
        int jj = j + dj - 1;
        if (jj < 0 || jj >= H_) continue;
        int f = c*9 + di*3 + dj;
        int kh = f / 192, kw = (f % 192) / 64, cc = f & 63;
        s += x[(((size_t)b*CIN + c)*H_ + ii)*H_ + jj] *
             K[(((size_t)kh*3 + kw)*CIN + cc)*COUT + co];
      }
    }
  out[idx] = s;
}

extern "C" void kernel_launch(void* const* d_in, const int* in_sizes, int n_in,
                              void* d_out, int out_size, void* d_ws, size_t ws_size,
                              hipStream_t stream) {
  const float* x = (const float*)d_in[0];
  const float* K = (const float*)d_in[1];
  float* out = (float*)d_out;
  if (ws_size >= WS_NEEDED) {
    __hip_bfloat16* xpT = (__hip_bfloat16*)d_ws;
    __hip_bfloat16* WgT = xpT + XP_TOTAL;
    prep_all<<<NROW + 1 + NWBLK, 256, 0, stream>>>(x, K, xpT, WgT);
    conv_mfma<<<B_*14, 256, 0, stream>>>(xpT, WgT, out);
  } else {
    conv_naive<<<(B_*COUT*H_*H_ + 255)/256, 256, 0, stream>>>(x, K, out);
  }
}

// Round 10
// 39.552 us; speedup vs baseline: 1.4617x; 1.0041x over previous
//
#include <hip/hip_runtime.h>
#include <hip/hip_bf16.h>
#include <stdint.h>

// Conv2d, B=32, Cin=64, Cout=128, 3x3, stride 1, pad 1, H=W=56, fp32 in/out.
// Reference's mismatched flatten == standard conv with permuted weights:
// Weff for patch elem (c,di,dj) = K[f/192][(f%192)/64][f%64], f = c*9+di*3+dj.
// Reduction order g = di*192 + dj*64 + c => for fixed di, A's K-slice is
// CONTIGUOUS in padded-NHWC layout: byte (w*64+c)*2 within row (i+di).
// r10: break the barrier LOCKSTEP — B fragments for chunk hc+1 are ds_read
// into registers BEFORE the MFMA cluster of chunk hc, so the LDS phase and
// MFMA phase overlap (r3-r9 all serialized them: ~2400cy/iter -> ~1300).
// 3 B buffers, stage 2 ahead, counted vmcnt, raw s_barrier + sched_barrier.

#define B_   32
#define CIN  64
#define COUT 128
#define H_   56
#define HP   58          // spatially padded
#define F_   576         // 9*64 reduction length

typedef __attribute__((ext_vector_type(8))) short bf16x8;
typedef __attribute__((ext_vector_type(4))) float f32x4;

#define XP_ELEMS (B_*HP*HP*CIN)          // 6,889,472
#define XP_SLACK 4096
#define XP_TOTAL (XP_ELEMS + XP_SLACK)
#define WG_ELEMS (COUT*F_)               // 73,728
#define WS_NEEDED ((size_t)(XP_TOTAL + WG_ELEMS) * 2)

#define NROW   (B_*HP)                   // 1856 x-row blocks
#define NWBLK  (WG_ELEMS/256)            // 288 weight blocks

// conv LDS (bytes): A tile [0, 45568); B frag bufs at 45568 + buf*8192 (x3).
#define A_ALLOC 45568
#define LDS_TOT (A_ALLOC + 3*8192)       // 70,144

// ---------- fused prepass: x NCHW f32 -> padded NHWC bf16; K -> WgT[co][g] ----
__global__ __launch_bounds__(256) void prep_all(const float* __restrict__ x,
                                                const float* __restrict__ K,
                                                __hip_bfloat16* __restrict__ xpT,
                                                __hip_bfloat16* __restrict__ WgT) {
  const int id = blockIdx.x;
  const int t  = threadIdx.x;

  if (id > NROW) {                       // ---- weight permute blocks ----
    int n = (id - (NROW + 1))*256 + t;   // 288 full blocks
    int co = n / F_, g = n % F_;
    int di = g / 192, dj = (g % 192) / 64, c = g & 63;
    int f  = c*9 + di*3 + dj;
    int kh = f / 192, kw = (f % 192) / 64, cc = f & 63;
    WgT[n] = __float2bfloat16(K[(((size_t)kh*3 + kw)*CIN + cc)*COUT + co]);
    return;
  }
  if (id == NROW) {                      // ---- slack zero-fill ----
    bf16x8 z = (bf16x8)0;
    for (int idx = t; idx < XP_SLACK/8; idx += 256)
      ((bf16x8*)(xpT + XP_ELEMS))[idx] = z;
    return;
  }

  const int b = id / HP, h = id % HP;
  __hip_bfloat16* orow = xpT + (size_t)(b*HP + h) * HP * CIN;
  if (h == 0 || h == HP-1) {             // top/bottom pad rows
    bf16x8 z = (bf16x8)0;
    for (int idx = t; idx < HP*CIN/8; idx += 256) ((bf16x8*)orow)[idx] = z;
    return;
  }
  // slot-swizzled scratch: scr[c][slot][4], slot = (w4 + (c>>3)) & 15.
  __shared__ __align__(16) float scr[CIN*64];      // 16 KB
  const float* xrow = x + ((size_t)(b*CIN)*H_ + (h-1)) * H_;
  for (int idx = t; idx < CIN*14; idx += 256) {    // coalesced f32x4 reads
    int c = idx / 14, w4 = idx % 14;
    f32x4 v = *(const f32x4*)(xrow + (size_t)c*(H_*H_) + w4*4);
    *(f32x4*)&scr[c*64 + ((w4 + (c >> 3)) & 15)*4] = v;
  }
  __syncthreads();
  for (int idx = t; idx < HP*8; idx += 256) {      // bf16x8 writes
    int wp = idx >> 3, cg = (idx & 7) * 8;
    __align__(16) __hip_bfloat16 tmp[8];
    if (wp == 0 || wp == HP-1) {
#pragma unroll
      for (int k2 = 0; k2 < 8; ++k2) tmp[k2] = __float2bfloat16(0.f);
    } else {
      int w = wp - 1, sl = w >> 2, off = w & 3;
#pragma unroll
      for (int k2 = 0; k2 < 8; ++k2) {
        int c = cg + k2;
        tmp[k2] = __float2bfloat16(scr[c*64 + ((sl + (c >> 3)) & 15)*4 + off]);
      }
    }
    *(bf16x8*)(orow + (size_t)wp*CIN + cg) = *(const bf16x8*)tmp;
  }
}

// ---------- main: implicit GEMM, block = (b, 4 rows), M=256(224 real), N=128
// A staged ONCE (XOR-swizzled src + reads, <=2-way = free). B triple-buffered
// 8KB half-chunks (k=32) in per-lane fragment order ([ni*1024+lane*16] ->
// linear reads, 0 conflicts), staged 2 ahead. Per iter: a-reads(hc), counted
// vmcnt + s_barrier, b_nxt-reads(hc+1), MFMA(hc) OVERLAPPING those reads,
// then stage(hc+3).
__global__ __launch_bounds__(256, 2) void conv_mfma(
    const __hip_bfloat16* __restrict__ xpT,
    const __hip_bfloat16* __restrict__ WgT,
    float* __restrict__ out) {
  __shared__ __align__(16) char lds[LDS_TOT];
  const int t    = threadIdx.x;
  const int wave = t >> 6;               // wave w -> output row i0+w
  const int l    = t & 63;
  const int lr   = l & 15, lq = l >> 4;

  // bijective XCD swizzle: 448 = 8 * 56
  const int bid = blockIdx.x;
  const int swz = (bid & 7) * 56 + (bid >> 3);
  const int bb  = swz / 14;
  const int i0  = (swz % 14) * 4;

  f32x4 acc[4][8];
#pragma unroll
  for (int mi = 0; mi < 4; ++mi)
#pragma unroll
    for (int ni = 0; ni < 8; ++ni) acc[mi][ni] = (f32x4)0.f;

  const char* xb    = (const char*)xpT + (size_t)(bb*HP + i0) * HP * CIN * 2;
  const char* wbase = (const char*)WgT;

  // ---- stage A once: 45,056 B contiguous, swizzled source, linear dest ----
#pragma unroll
  for (int s = 0; s < 11; ++s) {
    int o = s*4096 + t*16;
    int m = o >> 7;
    const char* src = xb + ((o & ~127) | ((o & 127) ^ ((m & 7) << 4)));
    __builtin_amdgcn_global_load_lds(
        (const __attribute__((address_space(1))) void*)src,
        (__attribute__((address_space(3))) void*)(lds + s*4096 + wave*1024),
        16, 0, 0);
  }

  // B staging source offsets: frag f = s*256+t -> ni = f>>6, lane = f&63;
  // co = ni*16 + (lane&15); src = WgT + hc*64 + co*1152 + (lane>>4)*16.
  int bsrc[2];
#pragma unroll
  for (int s = 0; s < 2; ++s) {
    int f  = s*256 + t;
    int ll = f & 63;
    int co = ((f >> 6)*16) + (ll & 15);
    bsrc[s] = co*1152 + ((ll >> 4)*16);
  }

  auto stageBh = [&](int hc) {           // 8 KB: WgT[*][hc*32 .. +32) frags
    const char* wg = wbase + hc*64;
    char* Bb = lds + A_ALLOC + (hc % 3)*8192;
#pragma unroll
    for (int s = 0; s < 2; ++s) {
      __builtin_amdgcn_global_load_lds(
          (const __attribute__((address_space(1))) void*)(wg + bsrc[s]),
          (__attribute__((address_space(3))) void*)(Bb + s*4096 + wave*1024),
          16, 0, 0);
    }
  };

  // prologue: stage B chunks 0,1,2; wait A+B0 (leave B1,B2 in flight)
  stageBh(0); stageBh(1); stageBh(2);
  asm volatile("s_waitcnt vmcnt(4)" ::: "memory");
  __builtin_amdgcn_s_barrier();
  __builtin_amdgcn_sched_barrier(0);

  bf16x8 bcur[8], bnxt[8];
#pragma unroll
  for (int ni = 0; ni < 8; ++ni)
    bcur[ni] = *(const bf16x8*)(lds + A_ALLOC + (ni*64 + l)*16);

  // ---- main loop: 18 half-chunks of k=32 ----
#pragma unroll
  for (int hc = 0; hc < 18; ++hc) {
    const int kg  = hc*32;
    const int di  = kg / 192;
    const int rem = kg - di*192;         // dj*64 + c0 within di-slab
    bf16x8 a[4];
#pragma unroll
    for (int mi = 0; mi < 4; ++mi) {
      int r   = (wave + di)*HP + mi*16 + lr;
      int tot = r*128 + rem*2 + lq*16;
      int adr = (tot & ~127) | ((tot & 127) ^ (((tot >> 7) & 7) << 4));
      a[mi] = *(const bf16x8*)(lds + adr);
    }
    if (hc < 17) {
      // stage(hc+1) must be landed before reading it (all waves)
      if (hc == 16) asm volatile("s_waitcnt vmcnt(0)" ::: "memory");
      else          asm volatile("s_waitcnt vmcnt(2)" ::: "memory");
      __builtin_amdgcn_s_barrier();
      __builtin_amdgcn_sched_barrier(0);
      const char* Bn = lds + A_ALLOC + ((hc + 1) % 3)*8192;
#pragma unroll
      for (int ni = 0; ni < 8; ++ni)
        bnxt[ni] = *(const bf16x8*)(Bn + (ni*64 + l)*16);  // drains under MFMA
    }
    __builtin_amdgcn_s_setprio(1);
#pragma unroll
    for (int mi = 0; mi < 4; ++mi)
#pragma unroll
      for (int ni = 0; ni < 8; ++ni)
        acc[mi][ni] = __builtin_amdgcn_mfma_f32_16x16x32_bf16(
            a[mi], bcur[ni], acc[mi][ni], 0, 0, 0);
    __builtin_amdgcn_s_setprio(0);
    if (hc + 3 < 18) stageBh(hc + 3);    // into buf hc%3 (reads(hc) are done:
                                         // ordered by barrier(hc) + margin)
#pragma unroll
    for (int ni = 0; ni < 8; ++ni) bcur[ni] = bnxt[ni];   // SSA rename, free
  }

  // epilogue: C/D layout col=lane&15 -> co, row=(lane>>4)*4+reg -> j
  const int i = i0 + wave;
#pragma unroll
  for (int mi = 0; mi < 4; ++mi) {
    int j0 = mi*16 + lq*4;
    if (j0 < H_) {
#pragma unroll
      for (int ni = 0; ni < 8; ++ni) {
        int co = ni*16 + lr;
        float* dst = out + (((size_t)(bb*COUT + co))*H_ + i)*H_ + j0;
        *(f32x4*)dst = acc[mi][ni];
      }
    }
  }
}

// ---------- fallback (workspace too small): naive fp32 direct ----------
__global__ __launch_bounds__(256) void conv_naive(const float* __restrict__ x,
                                                  const float* __restrict__ K,
                                                  float* __restrict__ out) {
  int idx = blockIdx.x*256 + threadIdx.x;
  const int total = B_*COUT*H_*H_;
  if (idx >= total) return;
  int j = idx % H_, i = (idx / H_) % H_, co = (idx / (H_*H_)) % COUT, b = idx / (H_*H_*COUT);
  float s = 0.f;
  for (int c = 0; c < CIN; ++c)
    for (int di = 0; di < 3; ++di) {
      int ii = i + di - 1;
      if (ii < 0 || ii >= H_) continue;
      for (int dj = 0; dj < 3; ++dj) {
        int jj = j + dj - 1;
        if (jj < 0 || jj >= H_) continue;
        int f = c*9 + di*3 + dj;
        int kh = f / 192, kw = (f % 192) / 64, cc = f & 63;
        s += x[(((size_t)b*CIN + c)*H_ + ii)*H_ + jj] *
             K[(((size_t)kh*3 + kw)*CIN + cc)*COUT + co];
      }
    }
  out[idx] = s;
}

extern "C" void kernel_launch(void* const* d_in, const int* in_sizes, int n_in,
                              void* d_out, int out_size, void* d_ws, size_t ws_size,
                              hipStream_t stream) {
  const float* x = (const float*)d_in[0];
  const float* K = (const float*)d_in[1];
  float* out = (float*)d_out;
  if (ws_size >= WS_NEEDED) {
    __hip_bfloat16* xpT = (__hip_bfloat16*)d_ws;
    __hip_bfloat16* WgT = xpT + XP_TOTAL;
    prep_all<<<NROW + 1 + NWBLK, 256, 0, stream>>>(x, K, xpT, WgT);
    conv_mfma<<<B_*14, 256, 0, stream>>>(xpT, WgT, out);
  } else {
    conv_naive<<<(B_*COUT*H_*H_ + 255)/256, 256, 0, stream>>>(x, K, out);
  }
}